// Round 1
// baseline (265.526 us; speedup 1.0000x reference)
//
#include <hip/hip_runtime.h>

// SpectralConv3d — reference quirks (verified against einsum semantics):
//   fftn axes (2,3,4) = (D2, D3, CIN)  [NOT D1 -- D1 is merely sliced to 8]
//   einsum 'bcmnk,coijk->bomnk' sums i,j out of w  =>  W_eff[c,o,k] = sum_{i,j} w[c,o,i,j,k]
//   ifftn axes (2,3,4) = (f2->d2, f3->d3, o->cout), norm 1/(64*64*32)
//   output is identically ZERO for d1 >= 8 (112 of 128 MiB)

#define PI2F 6.28318530717958647692f

__device__ __forceinline__ void twmul_acc(float vx, float vy, int t, int N,
                                          float sign, float& re, float& im) {
    // accumulate (vx + i vy) * e^{sign * 2*pi*i * t / N}, t already reduced mod N
    float ang = sign * (PI2F / (float)N) * (float)t;
    float s, c;
    __sincosf(ang, &s, &c);
    re += vx * c - vy * s;
    im += vx * s + vy * c;
}

// W_eff[c][o][k] = sum_{i,j} (w_real + i w_imag)[c][o][i][j][k]
__global__ void k_weff(const float* __restrict__ wr, const float* __restrict__ wi,
                       float2* __restrict__ Weff) {
    int t = blockIdx.x * 256 + threadIdx.x;   // 32*32*8 = 8192
    if (t >= 8192) return;
    int base = (t >> 3) * 512 + (t & 7);      // (c*32+o)*512 + k ; ij stride 8
    float sr = 0.f, si = 0.f;
    #pragma unroll 8
    for (int ij = 0; ij < 64; ++ij) { sr += wr[base + ij * 8]; si += wi[base + ij * 8]; }
    Weff[t] = make_float2(sr, si);
}

// S1[b][d1][f2][d3][c] = sum_d2 x[b][d1][d2][d3][c] * e^{-2pi i f2 d2 / 64}
__global__ void k_dft_d2(const float* __restrict__ x, float2* __restrict__ S1) {
    int t = blockIdx.x * 256 + threadIdx.x;   // 2^19 = 524288
    int c  = t & 31;
    int d3 = (t >> 5) & 63;
    int f2 = (t >> 11) & 7;
    int d1 = (t >> 14) & 7;
    int b  = t >> 17;
    const float* xp = x + (size_t)b * 8388608 + (size_t)d1 * 131072 + d3 * 32 + c;
    float re = 0.f, im = 0.f;
    for (int d2 = 0; d2 < 64; ++d2) {
        float v = xp[d2 * 2048];
        twmul_acc(v, 0.f, (f2 * d2) & 63, 64, -1.f, re, im);
    }
    S1[t] = make_float2(re, im);
}

// S2[b][d1][f2][f3][c] = sum_d3 S1[...][d3][c] * e^{-2pi i f3 d3 / 64}
__global__ void k_dft_d3(const float2* __restrict__ S1, float2* __restrict__ S2) {
    int t = blockIdx.x * 256 + threadIdx.x;   // 2^16 = 65536
    int c  = t & 31;
    int f3 = (t >> 5) & 7;
    int hi = t >> 8;                          // (b*8+d1)*8+f2
    const float2* p = S1 + (size_t)hi * 2048 + c;
    float re = 0.f, im = 0.f;
    for (int d3 = 0; d3 < 64; ++d3) {
        float2 v = p[d3 * 32];
        twmul_acc(v.x, v.y, (f3 * d3) & 63, 64, -1.f, re, im);
    }
    S2[t] = make_float2(re, im);
}

// S3[b][d1][f2][f3][fc] = sum_c S2[...][c] * e^{-2pi i fc c / 32}
__global__ void k_dft_c(const float2* __restrict__ S2, float2* __restrict__ S3) {
    int t = blockIdx.x * 256 + threadIdx.x;   // 65536
    int fc = t & 31;
    int base = t & ~31;
    float re = 0.f, im = 0.f;
    for (int c = 0; c < 32; ++c) {
        float2 v = S2[base + c];
        twmul_acc(v.x, v.y, (fc * c) & 31, 32, -1.f, re, im);
    }
    S3[t] = make_float2(re, im);
}

// S4[b][d1][f2][f3][o] = sum_fc S3[...][fc] * Weff[fc][o][f3]
__global__ void k_mix(const float2* __restrict__ S3, const float2* __restrict__ Weff,
                      float2* __restrict__ S4) {
    int t = blockIdx.x * 256 + threadIdx.x;   // 65536
    int o  = t & 31;
    int f3 = (t >> 5) & 7;
    int base = t & ~31;
    float re = 0.f, im = 0.f;
    for (int fc = 0; fc < 32; ++fc) {
        float2 a = S3[base + fc];
        float2 w = Weff[(fc * 32 + o) * 8 + f3];
        re += a.x * w.x - a.y * w.y;
        im += a.x * w.y + a.y * w.x;
    }
    S4[t] = make_float2(re, im);
}

// S5[b][d1][f2][f3][co] = sum_o S4[...][o] * e^{+2pi i o co / 32}
__global__ void k_idft_c(const float2* __restrict__ S4, float2* __restrict__ S5) {
    int t = blockIdx.x * 256 + threadIdx.x;   // 65536
    int co = t & 31;
    int base = t & ~31;
    float re = 0.f, im = 0.f;
    for (int o = 0; o < 32; ++o) {
        float2 v = S4[base + o];
        twmul_acc(v.x, v.y, (o * co) & 31, 32, 1.f, re, im);
    }
    S5[t] = make_float2(re, im);
}

// S6[b][d1][f2][d3][co] = sum_f3 S5[b][d1][f2][f3][co] * e^{+2pi i f3 d3 / 64}
__global__ void k_idft_d3(const float2* __restrict__ S5, float2* __restrict__ S6) {
    int t = blockIdx.x * 256 + threadIdx.x;   // 2^19
    int co = t & 31;
    int d3 = (t >> 5) & 63;
    int bd1f2 = t >> 11;                      // in [0,256)
    const float2* p = S5 + bd1f2 * 256 + co;  // f3 stride 32
    float re = 0.f, im = 0.f;
    #pragma unroll
    for (int f3 = 0; f3 < 8; ++f3) {
        float2 v = p[f3 * 32];
        twmul_acc(v.x, v.y, (f3 * d3) & 63, 64, 1.f, re, im);
    }
    S6[t] = make_float2(re, im);
}

// out[b][d1][d2][d3][co] = (1/131072) * Re sum_f2 S6[b][d1][f2][d3][co] e^{+2pi i f2 d2/64}
// zero for d1 >= 8. float4 stores (4 consecutive co).
__global__ void k_final(const float2* __restrict__ S6, float* __restrict__ out) {
    int t4 = blockIdx.x * 256 + threadIdx.x;  // 2^23 = 8388608
    int u = t4 << 2;
    int co = u & 31;
    int d3 = (u >> 5) & 63;
    int d2 = (u >> 11) & 63;
    int d1 = (u >> 17) & 63;
    int b  = u >> 23;
    float4 r;
    if (d1 >= 8) {
        r = make_float4(0.f, 0.f, 0.f, 0.f);
    } else {
        const float2* q = S6 + (size_t)(b * 8 + d1) * 16384 + d3 * 32 + co;
        float a0 = 0.f, a1 = 0.f, a2 = 0.f, a3 = 0.f;
        #pragma unroll
        for (int f2 = 0; f2 < 8; ++f2) {
            float ang = (PI2F / 64.f) * (float)((f2 * d2) & 63);
            float s, c;
            __sincosf(ang, &s, &c);
            float2 v0 = q[f2 * 2048 + 0];
            float2 v1 = q[f2 * 2048 + 1];
            float2 v2 = q[f2 * 2048 + 2];
            float2 v3 = q[f2 * 2048 + 3];
            a0 += v0.x * c - v0.y * s;
            a1 += v1.x * c - v1.y * s;
            a2 += v2.x * c - v2.y * s;
            a3 += v3.x * c - v3.y * s;
        }
        const float sc = 1.f / 131072.f;
        r = make_float4(a0 * sc, a1 * sc, a2 * sc, a3 * sc);
    }
    ((float4*)out)[t4] = r;
}

extern "C" void kernel_launch(void* const* d_in, const int* in_sizes, int n_in,
                              void* d_out, int out_size, void* d_ws, size_t ws_size,
                              hipStream_t stream) {
    const float* x  = (const float*)d_in[0];
    const float* wr = (const float*)d_in[1];
    const float* wi = (const float*)d_in[2];
    float* out = (float*)d_out;

    float2* Weff = (float2*)d_ws;            // 8192
    float2* S1 = Weff + 8192;                // 524288
    float2* S2 = S1 + 524288;                // 65536
    float2* S3 = S2 + 65536;                 // 65536
    float2* S4 = S3 + 65536;                 // 65536
    float2* S5 = S4 + 65536;                 // 65536
    float2* S6 = S5 + 65536;                 // 524288  (total ~10.1 MiB)

    k_weff   <<<32,    256, 0, stream>>>(wr, wi, Weff);
    k_dft_d2 <<<2048,  256, 0, stream>>>(x, S1);
    k_dft_d3 <<<256,   256, 0, stream>>>(S1, S2);
    k_dft_c  <<<256,   256, 0, stream>>>(S2, S3);
    k_mix    <<<256,   256, 0, stream>>>(S3, Weff, S4);
    k_idft_c <<<256,   256, 0, stream>>>(S4, S5);
    k_idft_d3<<<2048,  256, 0, stream>>>(S5, S6);
    k_final  <<<32768, 256, 0, stream>>>(S6, out);
}

// Round 2
// 238.344 us; speedup vs baseline: 1.1140x; 1.1140x over previous
//
#include <hip/hip_runtime.h>

// SpectralConv3d — reference structure:
//   fftn axes (2,3,4) = (D2, D3, CIN); D1 only sliced to <8 (output zero for d1>=8)
//   einsum sums i,j out of w => Weff[c,o,k] = sum_ij w[c,o,i,j,k]
//   Algebraic fold: DFT_c + mix + IDFT_c == fixed map T[c][f3][co]
//   ifftn norm 1/(64*64*32) = 1/131072
//
// Pipeline: k_weff -> k_T (tiny), k_dft_d2 (x->S1), k_mid (S1->S6, fused), k_final (S6->out)

#define PI2F 6.28318530717958647692f

__device__ __forceinline__ float2 cmul(float2 a, float2 b) {
    return make_float2(a.x * b.x - a.y * b.y, a.x * b.y + a.y * b.x);
}

// Weff[fc][o][f3] = sum_{ij} (wr + i wi)[fc][o][i][j][f3]
__global__ void k_weff(const float* __restrict__ wr, const float* __restrict__ wi,
                       float2* __restrict__ Weff) {
    int t = blockIdx.x * 256 + threadIdx.x;   // 8192
    int base = (t >> 3) * 512 + (t & 7);      // (fc*32+o)*512 + f3; ij stride 8
    float sr = 0.f, si = 0.f;
    #pragma unroll 8
    for (int ij = 0; ij < 64; ++ij) { sr += wr[base + ij * 8]; si += wi[base + ij * 8]; }
    Weff[t] = make_float2(sr, si);
}

// T[c][f3][co] = sum_{fc,o} e^{-2pi i fc c/32} Weff[fc][o][f3] e^{+2pi i o co/32}
// one workgroup per c (32 wg). Stage A[o][f3] in LDS.
__global__ void k_T(const float2* __restrict__ Weff, float2* __restrict__ T) {
    __shared__ float2 tw32[32];
    __shared__ float2 A[256];
    int t = threadIdx.x;
    int c = blockIdx.x;
    if (t < 32) {
        float s, co_;
        __sincosf((PI2F / 32.f) * (float)t, &s, &co_);
        tw32[t] = make_float2(co_, s);
    }
    __syncthreads();
    // Stage 1: A[o][f3] = sum_fc Weff[fc][o][f3] * conj(tw32[fc*c])
    {
        float2 acc = make_float2(0.f, 0.f);
        for (int fc = 0; fc < 32; ++fc) {
            float2 v = Weff[fc * 256 + t];        // t = o*8+f3, contiguous
            float2 e = tw32[(fc * c) & 31];       // E^-( fc*c ): (cos, -sin)
            acc.x += v.x * e.x + v.y * e.y;
            acc.y += v.y * e.x - v.x * e.y;
        }
        A[t] = acc;
    }
    __syncthreads();
    // Stage 2: T[c][f3][co] = sum_o A[o][f3] * tw32[o*co]  (E^+)
    {
        int f3 = t >> 5, co = t & 31;
        float2 acc = make_float2(0.f, 0.f);
        for (int o = 0; o < 32; ++o) {
            float2 v = A[o * 8 + f3];
            float2 e = tw32[(o * co) & 31];       // E^+: (cos, +sin)
            acc.x += v.x * e.x - v.y * e.y;
            acc.y += v.x * e.y + v.y * e.x;
        }
        T[c * 256 + t] = acc;                     // layout [c][f3][co]
    }
}

// S1[b][d1][f2][d3][c] = sum_d2 x[b][d1][d2][d3][c] e^{-2pi i f2 d2/64}
// thread per (b,d1,f2,d3,c4): float4 loads, recurrence twiddle.
__global__ void k_dft_d2(const float* __restrict__ x, float2* __restrict__ S1) {
    int t = blockIdx.x * 256 + threadIdx.x;   // 131072
    int c4 = t & 7;
    int d3 = (t >> 3) & 63;
    int f2 = (t >> 9) & 7;
    int d1 = (t >> 12) & 7;
    int b  = t >> 15;
    const float4* xp = (const float4*)(x + (size_t)b * 8388608 + (size_t)d1 * 131072
                                         + d3 * 32 + c4 * 4);
    float s, c;
    __sincosf((PI2F / 64.f) * (float)f2, &s, &c);
    float2 step = make_float2(c, -s);         // e^{-2pi i f2/64}
    float2 w = make_float2(1.f, 0.f);
    float2 a0 = {0,0}, a1 = {0,0}, a2 = {0,0}, a3 = {0,0};
    for (int d2 = 0; d2 < 64; ++d2) {
        float4 v = xp[d2 * 512];              // 2048 floats = 512 float4
        a0.x += v.x * w.x; a0.y += v.x * w.y;
        a1.x += v.y * w.x; a1.y += v.y * w.y;
        a2.x += v.z * w.x; a2.y += v.z * w.y;
        a3.x += v.w * w.x; a3.y += v.w * w.y;
        w = cmul(w, step);
    }
    float2* sp = S1 + (size_t)(t >> 9) * 2048 + d3 * 32 + c4 * 4;
    ((float4*)sp)[0] = make_float4(a0.x, a0.y, a1.x, a1.y);
    ((float4*)sp)[1] = make_float4(a2.x, a2.y, a3.x, a3.y);
}

// Fused middle: per (b,d1,f2) slab (256 wg):
//   LDS <- S1 slab [d3=64][c=32]
//   S2[f3][c]  = sum_d3 slab * E64^-(f3 d3)     (recurrence)
//   S5[f3][co] = sum_c  S2 * T[c][f3][co]       (coalesced global T)
//   S6[d3][co] = sum_f3 S5 * E64^+(f3 d3)       (table)
__global__ void k_mid(const float2* __restrict__ S1, const float2* __restrict__ T,
                      float2* __restrict__ S6) {
    __shared__ float2 lin[2048];    // [d3][c]
    __shared__ float2 ls2[256];     // [f3][c]
    __shared__ float2 ls5[256];     // [f3][co]
    __shared__ float2 tw64[64];
    int t = threadIdx.x;
    int gid = blockIdx.x;
    // load slab (1024 float4)
    {
        const float4* src = (const float4*)(S1 + (size_t)gid * 2048);
        float4* dst = (float4*)lin;
        #pragma unroll
        for (int j = 0; j < 4; ++j) dst[t + j * 256] = src[t + j * 256];
    }
    if (t < 64) {
        float s, c;
        __sincosf((PI2F / 64.f) * (float)t, &s, &c);
        tw64[t] = make_float2(c, s);
    }
    __syncthreads();
    // Stage A: t -> (f3 = t>>5, c = t&31)
    {
        int f3 = t >> 5, c = t & 31;
        float2 e = tw64[f3];
        float2 step = make_float2(e.x, -e.y);   // e^{-2pi i f3/64}
        float2 w = make_float2(1.f, 0.f);
        float2 acc = make_float2(0.f, 0.f);
        for (int d3 = 0; d3 < 64; ++d3) {
            float2 v = lin[d3 * 32 + c];
            acc.x += v.x * w.x - v.y * w.y;
            acc.y += v.x * w.y + v.y * w.x;
            w = cmul(w, step);
        }
        ls2[f3 * 32 + c] = acc;
    }
    __syncthreads();
    // Stage B: t -> (f3 = t>>5, co = t&31); T layout [c][f3][co]
    {
        int f3 = t >> 5;
        float2 acc = make_float2(0.f, 0.f);
        for (int c = 0; c < 32; ++c) {
            float2 a = ls2[f3 * 32 + (c)];
            float2 w = T[c * 256 + t];
            acc.x += a.x * w.x - a.y * w.y;
            acc.y += a.x * w.y + a.y * w.x;
        }
        ls5[t] = acc;
    }
    __syncthreads();
    // Stage C: thread -> (co = t&31, d3r = t>>5); d3 = d3r + 8*j
    {
        int co = t & 31, d3r = t >> 5;
        float2* outp = S6 + (size_t)gid * 2048;
        #pragma unroll
        for (int j = 0; j < 8; ++j) {
            int d3 = d3r + 8 * j;
            float2 acc = make_float2(0.f, 0.f);
            #pragma unroll
            for (int f3 = 0; f3 < 8; ++f3) {
                float2 v = ls5[f3 * 32 + co];
                float2 e = tw64[(f3 * d3) & 63];   // E^+
                acc.x += v.x * e.x - v.y * e.y;
                acc.y += v.x * e.y + v.y * e.x;
            }
            outp[d3 * 32 + co] = acc;
        }
    }
}

// out[b][d1][d2][d3][co] = (1/131072) * Re sum_f2 S6[(b,d1)][f2][d3][co] E^+(f2 d2)
// zero for d1 >= 8. float4 stores.
__global__ void k_final(const float2* __restrict__ S6, float* __restrict__ out) {
    int t4 = blockIdx.x * 256 + threadIdx.x;  // 8388608
    int u = t4 << 2;
    int co = u & 31;
    int d3 = (u >> 5) & 63;
    int d2 = (u >> 11) & 63;
    int d1 = (u >> 17) & 63;
    int b  = u >> 23;
    float4 r;
    if (d1 >= 8) {
        r = make_float4(0.f, 0.f, 0.f, 0.f);
    } else {
        const float2* q = S6 + (size_t)(b * 8 + d1) * 16384 + d3 * 32 + co;
        float a0 = 0.f, a1 = 0.f, a2 = 0.f, a3 = 0.f;
        #pragma unroll
        for (int f2 = 0; f2 < 8; ++f2) {
            float ang = (PI2F / 64.f) * (float)((f2 * d2) & 63);
            float s, c;
            __sincosf(ang, &s, &c);
            float2 v0 = q[f2 * 2048 + 0];
            float2 v1 = q[f2 * 2048 + 1];
            float2 v2 = q[f2 * 2048 + 2];
            float2 v3 = q[f2 * 2048 + 3];
            a0 += v0.x * c - v0.y * s;
            a1 += v1.x * c - v1.y * s;
            a2 += v2.x * c - v2.y * s;
            a3 += v3.x * c - v3.y * s;
        }
        const float sc = 1.f / 131072.f;
        r = make_float4(a0 * sc, a1 * sc, a2 * sc, a3 * sc);
    }
    ((float4*)out)[t4] = r;
}

extern "C" void kernel_launch(void* const* d_in, const int* in_sizes, int n_in,
                              void* d_out, int out_size, void* d_ws, size_t ws_size,
                              hipStream_t stream) {
    const float* x  = (const float*)d_in[0];
    const float* wr = (const float*)d_in[1];
    const float* wi = (const float*)d_in[2];
    float* out = (float*)d_out;

    float2* Weff = (float2*)d_ws;            // 8192
    float2* T    = Weff + 8192;              // 8192
    float2* S1   = T + 8192;                 // 524288 (4 MiB)
    float2* S6   = S1 + 524288;              // 524288 (4 MiB)  total ~8.1 MiB

    k_weff  <<<32,    256, 0, stream>>>(wr, wi, Weff);
    k_T     <<<32,    256, 0, stream>>>(Weff, T);
    k_dft_d2<<<512,   256, 0, stream>>>(x, S1);
    k_mid   <<<256,   256, 0, stream>>>(S1, T, S6);
    k_final <<<32768, 256, 0, stream>>>(S6, out);
}